// Round 8
// baseline (1192.742 us; speedup 1.0000x reference)
//
#include <hip/hip_runtime.h>
#include <hip/hip_bf16.h>
#include <cfloat>

// VecPointNet on MI355X, round 8:
//  - kNN restored to r6 (ballot + wave-shared sorted list, measured 83us).
//  - All 4 layers + yg + bias + Wout + final mean fused into ONE persistent
//    mega-kernel (256 blocks = 1/CU co-resident) with device-scope atomic grid
//    barriers. Replaces ~21 dispatches with 1 (kills launch-gap serialization).
//  - prep + pack fused into one setup kernel (also zeroes the barrier counter
//    every call -> deterministic under graph replay).
//  Dispatches: setup, knn, edge, mega  (4 total).

typedef __attribute__((ext_vector_type(8))) short short8;
typedef __attribute__((ext_vector_type(4))) float f32x4;

__device__ __forceinline__ unsigned short f2bf(float f) {
    union { float f; unsigned u; } v; v.f = f;
    unsigned r = v.u + 0x7fffu + ((v.u >> 16) & 1u);
    return (unsigned short)(r >> 16);
}
__device__ __forceinline__ float bf2f(unsigned short h) {
    union { unsigned u; float f; } v; v.u = ((unsigned)h) << 16;
    return v.f;
}

// ---------------- grid barrier (monotonic counter, device scope) ----------------
__device__ __forceinline__ void grid_bar(int* bar, int target) {
    __threadfence();                 // release: drain this thread's writes
    __syncthreads();
    if (threadIdx.x == 0) {
        atomicAdd(bar, 1);
        while (atomicAdd(bar, 0) < target) __builtin_amdgcn_s_sleep(8);
    }
    __syncthreads();
    __threadfence();                 // acquire: invalidate caches before reads
}

// ---------------- setup: prep (pts4) + weight pack + barrier reset ----------------
__global__ __launch_bounds__(256) void setup_kernel(const float* __restrict__ x,
                                                    float4* __restrict__ pts4,
                                                    const float* __restrict__ Wl,
                                                    const float* __restrict__ Ul,
                                                    const float* __restrict__ Wg,
                                                    const float* __restrict__ Ug,
                                                    const float* __restrict__ Wout,
                                                    unsigned short* __restrict__ Ah,
                                                    unsigned short* __restrict__ Al,
                                                    int* __restrict__ bar,
                                                    int N, int B) {
    int t = blockIdx.x * 256 + threadIdx.x;     // 0..327679
    if (t == 0) *bar = 0;
    if (t < B * N) {
        int b = t / N, n = t - b * N;
        const float* xb = x + (long)b * 3 * N;
        float px = xb[n], py = xb[N + n], pz = xb[2 * N + n];
        pts4[t] = make_float4(px, py, pz, px * px + py * py + pz * pz);
    }
    // ---- pack ----
    int g, r, M; long base;
    if (t < 262144) { g = t >> 15; r = t & 32767; M = 256; base = (long)g << 15; }
    else { int t2 = t - 262144; g = 8 + (t2 >> 14); r = t2 & 16383; M = 128;
           base = 262144 + (long)(g - 8) * 16384; }
    int MF = M >> 4;
    int ks = r / (MF * 512);
    int mf = (r >> 9) % MF;
    int lane = (r >> 3) & 63;
    int j = r & 7;
    int m = mf * 16 + (lane & 15);
    int k = ks * 32 + ((lane >> 4) << 3) + j;
    const float* src; int ldw; int row;
    if (g < 4) {
        ldw = 128; row = m & 127;
        src = (m < 128) ? (Wl + (long)g * 128 * 128) : (Ul + (long)g * 128 * 128);
    } else if (g < 8) {
        ldw = 256; row = m & 127;
        int l = g - 4;
        src = (m < 128) ? (Wg + (long)l * 128 * 256) : (Ug + (long)l * 128 * 256);
    } else {
        ldw = 512; row = m;
        src = Wout + (g - 8) * 128;
    }
    float v = src[(long)row * ldw + k];
    unsigned short h = f2bf(v);
    Ah[base + r] = h;
    Al[base + r] = f2bf(v - bf2f(h));
}

// ---------------- knn (r6 version): one wave per query, ballot top-16, x2 unroll ----------------
__global__ __launch_bounds__(1024) void knn_kernel(const float4* __restrict__ pts4,
                                                   int* __restrict__ idxOut, int N) {
    __shared__ float4 cbuf[4096];   // 64 KB
    int t = threadIdx.x;
    int tilesPerB = N / 16;
    int b = blockIdx.x / tilesPerB;
    int q = (blockIdx.x % tilesPerB) * 16 + (t >> 6);
    int lane = t & 63;

    for (int i = t; i < N; i += 1024) cbuf[i] = pts4[b * N + i];
    __syncthreads();

    float4 Q = cbuf[q];
    double k = 1e300;     // lanes 0..15: sorted ascending top-16 keys
    double T = 1e300;     // current 16th-best key (uniform)

#define KNN_INSERT(KEYV)                                              \
    {                                                                 \
        unsigned long long mask = __ballot((KEYV) < T);               \
        while (mask) {                                                \
            int src = __ffsll(mask) - 1;                              \
            mask &= mask - 1;                                         \
            double vb = __shfl((KEYV), src);                          \
            if (vb < T) {                                             \
                double km1 = __shfl_up(k, 1);                         \
                if (lane == 0) km1 = -1.0;                            \
                double kn = (vb <= km1) ? km1 : ((vb < k) ? vb : k);  \
                if (lane < 16) k = kn;                                \
                T = __shfl(k, 15);                                    \
            }                                                         \
        }                                                             \
    }

    for (int c0 = 0; c0 < N; c0 += 128) {
        float4 Ca = cbuf[c0 + lane];
        float4 Cb = cbuf[c0 + 64 + lane];
        float dota = Q.x * Ca.x + Q.y * Ca.y + Q.z * Ca.z;
        float dotb = Q.x * Cb.x + Q.y * Cb.y + Q.z * Cb.z;
        float d2a = Q.w + Ca.w - 2.0f * dota;       // same formula as reference
        float d2b = Q.w + Cb.w - 2.0f * dotb;
        unsigned ua = __float_as_uint(d2a);
        unsigned ub = __float_as_uint(d2b);
        ua ^= (unsigned)((int)ua >> 31) | 0x80000000u;  // orderable uint
        ub ^= (unsigned)((int)ub >> 31) | 0x80000000u;
        double keya = (double)ua * 4096.0 + (double)(c0 + lane);
        double keyb = (double)ub * 4096.0 + (double)(c0 + 64 + lane);
        KNN_INSERT(keya);
        KNN_INSERT(keyb);
    }
#undef KNN_INSERT

    if (lane < 16) {
        long long kl = (long long)k;                 // exact (key < 2^44)
        idxOut[(b * N + q) * 16 + lane] = (int)(kl & 4095);
    }
}

// ---------------- edge features + input LNA + mean over K -> f0 bf16 hi/lo ----------------
__global__ __launch_bounds__(256) void edge_kernel(const float4* __restrict__ pts4,
                                                   const int* __restrict__ idx,
                                                   const float* __restrict__ Win,
                                                   const float* __restrict__ Uin,
                                                   unsigned short* __restrict__ Yh,
                                                   unsigned short* __restrict__ Yl,
                                                   int N) {
    __shared__ float4 nbuf[8][16];
    __shared__ float4 cpt[8];
    int nTiles = N / 8;
    int b = blockIdx.x / nTiles;
    int n0 = (blockIdx.x % nTiles) * 8;
    int t = threadIdx.x;
    if (t < 128) {
        int pl = t >> 4, k = t & 15;
        int nb = idx[(b * N + n0 + pl) * 16 + k];
        nbuf[pl][k] = pts4[b * N + nb];
    } else if (t < 136) {
        cpt[t - 128] = pts4[b * N + n0 + (t - 128)];
    }
    __syncthreads();
    int o = t & 127, h = t >> 7;
    float w0 = Win[o * 3], w1 = Win[o * 3 + 1], w2 = Win[o * 3 + 2];
    float u0 = Uin[o * 3], u1 = Uin[o * 3 + 1], u2 = Uin[o * 3 + 2];
    for (int pl = h * 4; pl < h * 4 + 4; ++pl) {
        float4 c4 = cpt[pl];
        float inv = 1.0f / fmaxf(sqrtf(c4.w), 1e-12f);
        float ax = c4.x * inv, ay = c4.y * inv, az = c4.z * inv;
        float a0 = 0.f, a1 = 0.f, a2 = 0.f;
        for (int k = 0; k < 16; ++k) {
            float4 nb = nbuf[pl][k];
            float cr0 = ay * nb.z - az * nb.y;
            float cr1 = az * nb.x - ax * nb.z;
            float cr2 = ax * nb.y - ay * nb.x;
            float df0 = nb.x - c4.x, df1 = nb.y - c4.y, df2 = nb.z - c4.z;
            float P0 = w0 * cr0 + w1 * df0 + w2 * c4.x;
            float P1 = w0 * cr1 + w1 * df1 + w2 * c4.y;
            float P2 = w0 * cr2 + w1 * df2 + w2 * c4.z;
            float D0 = u0 * cr0 + u1 * df0 + u2 * c4.x;
            float D1 = u0 * cr1 + u1 * df1 + u2 * c4.y;
            float D2 = u0 * cr2 + u1 * df2 + u2 * c4.z;
            float dot = P0 * D0 + P1 * D1 + P2 * D2;
            float dsq = D0 * D0 + D1 * D1 + D2 * D2;
            if (dot < 0.0f) {
                float s = dot / (dsq + 1e-6f);
                P0 -= s * D0; P1 -= s * D1; P2 -= s * D2;
            }
            a0 += P0; a1 += P1; a2 += P2;
        }
        float vals[3] = { a0 * (1.0f / 16.0f), a1 * (1.0f / 16.0f), a2 * (1.0f / 16.0f) };
        long n = n0 + pl;
#pragma unroll
        for (int c = 0; c < 3; ++c) {
            long off = ((long)(b * 3 + c) * 4096 + n) * 128 + o;
            unsigned short hh = f2bf(vals[c]);
            Yh[off] = hh;
            Yl[off] = f2bf(vals[c] - bf2f(hh));
        }
    }
}

// ---------------- mega: 4x [gemm0 -> bar -> yg -> bar -> bias+gemm1+Wout -> bar] + out0 ----------------
// 256 blocks x 512 threads, 1 block/CU (co-resident), launch_bounds(512,2) caps VGPR at 256.
__global__ __launch_bounds__(512, 2) void mega_kernel(
    const unsigned short* __restrict__ Aph, const unsigned short* __restrict__ Apl,
    unsigned short* __restrict__ f0h, unsigned short* __restrict__ f0l,
    unsigned short* __restrict__ y1h, unsigned short* __restrict__ y1l,
    const float* __restrict__ Wg, const float* __restrict__ Ug,
    float* __restrict__ part, float* __restrict__ yg,
    float* __restrict__ out1, float* __restrict__ out0,
    int* __restrict__ bar)
{
    const int N = 4096;
    __shared__ unsigned short ylds[2][3][2][2048];   // 48 KB: y2 staging for Wout
    __shared__ float biasPs[128][3];                 // 1.5 KB
    __shared__ float biasDs[128][3];                 // 1.5 KB
    __shared__ float ygs[384];                       // 1.5 KB
    __shared__ float red[4][128];                    // 2 KB

    int t = threadIdx.x;
    int lane = t & 63, w = t >> 6;
    int mg = w >> 1, ng = w & 1;
    int b = blockIdx.x >> 7;
    int tile = blockIdx.x & 127;
    int ncol = tile * 32 + ng * 16 + (lane & 15);
    int kq = (lane >> 4) << 3;
    int nbar = 0;

    for (int l = 0; l < 4; ++l) {
        // ================= phase A: y1 = LNA(Wl f0, Ul f0) + yg partials =================
        {
            const unsigned short* AhB = Aph + (long)l * 32768;
            const unsigned short* AlB = Apl + (long)l * 32768;
            f32x4 accP[2][3] = {};
            f32x4 accD[2][3] = {};
#pragma unroll
            for (int ks = 0; ks < 4; ++ks) {
                short8 bh[3], bl[3];
#pragma unroll
                for (int c = 0; c < 3; ++c) {
                    long boff = ((long)(b * 3 + c) * N + ncol) * 128 + ks * 32 + kq;
                    bh[c] = *(const short8*)(f0h + boff);
                    bl[c] = *(const short8*)(f0l + boff);
                }
#pragma unroll
                for (int pi = 0; pi < 2; ++pi) {
                    int mf = 2 * mg + pi;
                    long aoffP = (((long)ks * 16 + mf) * 64 + lane) * 8;
                    short8 ahP = *(const short8*)(AhB + aoffP);
                    short8 alP = *(const short8*)(AlB + aoffP);
#pragma unroll
                    for (int c = 0; c < 3; ++c) {
                        accP[pi][c] = __builtin_amdgcn_mfma_f32_16x16x32_bf16(ahP, bh[c], accP[pi][c], 0, 0, 0);
                        accP[pi][c] = __builtin_amdgcn_mfma_f32_16x16x32_bf16(ahP, bl[c], accP[pi][c], 0, 0, 0);
                        accP[pi][c] = __builtin_amdgcn_mfma_f32_16x16x32_bf16(alP, bh[c], accP[pi][c], 0, 0, 0);
                    }
                    long aoffD = (((long)ks * 16 + (8 + mf)) * 64 + lane) * 8;
                    short8 ahD = *(const short8*)(AhB + aoffD);
                    short8 alD = *(const short8*)(AlB + aoffD);
#pragma unroll
                    for (int c = 0; c < 3; ++c) {
                        accD[pi][c] = __builtin_amdgcn_mfma_f32_16x16x32_bf16(ahD, bh[c], accD[pi][c], 0, 0, 0);
                        accD[pi][c] = __builtin_amdgcn_mfma_f32_16x16x32_bf16(ahD, bl[c], accD[pi][c], 0, 0, 0);
                        accD[pi][c] = __builtin_amdgcn_mfma_f32_16x16x32_bf16(alD, bh[c], accD[pi][c], 0, 0, 0);
                    }
                }
            }
#pragma unroll
            for (int pi = 0; pi < 2; ++pi) {
                int obase = 32 * mg + 16 * pi + ((lane >> 4) << 2);
                float Pv[3][4];
#pragma unroll
                for (int r = 0; r < 4; ++r) {
                    float P[3], D[3];
#pragma unroll
                    for (int c = 0; c < 3; ++c) { P[c] = accP[pi][c][r]; D[c] = accD[pi][c][r]; }
                    float dot = P[0] * D[0] + P[1] * D[1] + P[2] * D[2];
                    float dsq = D[0] * D[0] + D[1] * D[1] + D[2] * D[2];
                    if (dot < 0.0f) {
                        float s = dot / (dsq + 1e-6f);
                        P[0] -= s * D[0]; P[1] -= s * D[1]; P[2] -= s * D[2];
                    }
                    Pv[0][r] = P[0]; Pv[1][r] = P[1]; Pv[2][r] = P[2];
                }
#pragma unroll
                for (int c = 0; c < 3; ++c) {
                    unsigned short hs[4], ls[4];
#pragma unroll
                    for (int r = 0; r < 4; ++r) {
                        hs[r] = f2bf(Pv[c][r]);
                        ls[r] = f2bf(Pv[c][r] - bf2f(hs[r]));
                    }
                    long ooff = ((long)(b * 3 + c) * N + ncol) * 128 + obase;
                    *(ushort4*)(y1h + ooff) = make_ushort4(hs[0], hs[1], hs[2], hs[3]);
                    *(ushort4*)(y1l + ooff) = make_ushort4(ls[0], ls[1], ls[2], ls[3]);
                }
                // yg partials (segment = tile*2+ng)
#pragma unroll
                for (int c = 0; c < 3; ++c) {
#pragma unroll
                    for (int r = 0; r < 4; ++r) {
                        float v = Pv[c][r];
                        v += __shfl_xor(v, 1);
                        v += __shfl_xor(v, 2);
                        v += __shfl_xor(v, 4);
                        v += __shfl_xor(v, 8);
                        if ((lane & 15) == 0)
                            part[((long)(b * 3 + c) * 256 + tile * 2 + ng) * 128 + (obase + r)] = v;
                    }
                }
            }
        }
        grid_bar(bar, 256 * (++nbar));

        // ================= phase B: yg reduce (blocks 0..5) =================
        if (blockIdx.x < 6) {
            int bc = blockIdx.x;
            int o = t & 127, g = t >> 7;     // 4 groups x 64 segments
            float s = 0.f;
            for (int seg = g * 64; seg < g * 64 + 64; ++seg)
                s += part[((long)bc * 256 + seg) * 128 + o];
            red[g][o] = s;
            __syncthreads();
            if (t < 128) {
                float r = red[0][t] + red[1][t] + red[2][t] + red[3][t];
                int bb = bc / 3, cc = bc % 3;
                yg[((long)(bb * 128) + t) * 3 + cc] = r * (1.0f / 4096.0f);
            }
        }
        grid_bar(bar, 256 * (++nbar));

        // ================= phase C: bias (redundant, LDS) + gemm1 + Wout =================
        if (t < 384) ygs[t] = yg[b * 384 + t];   // (b*128+i)*3+c contiguous
        __syncthreads();
        if (t < 384) {
            int o = t / 3, c = t - o * 3;
            const float* wrow = Wg + (long)l * 32768 + o * 256 + 128;
            const float* urow = Ug + (long)l * 32768 + o * 256 + 128;
            float sp = 0.f, sd = 0.f;
            for (int i = 0; i < 128; ++i) {
                float y = ygs[i * 3 + c];
                sp = fmaf(wrow[i], y, sp);
                sd = fmaf(urow[i], y, sd);
            }
            biasPs[o][c] = sp; biasDs[o][c] = sd;
        }
        __syncthreads();
        {
            const unsigned short* AhB = Aph + (long)(4 + l) * 32768;
            const unsigned short* AlB = Apl + (long)(4 + l) * 32768;
            f32x4 accP[2][3] = {};
            f32x4 accD[2][3] = {};
#pragma unroll
            for (int ks = 0; ks < 4; ++ks) {
                short8 bh[3], bl[3];
#pragma unroll
                for (int c = 0; c < 3; ++c) {
                    long boff = ((long)(b * 3 + c) * N + ncol) * 128 + ks * 32 + kq;
                    bh[c] = *(const short8*)(y1h + boff);
                    bl[c] = *(const short8*)(y1l + boff);
                }
#pragma unroll
                for (int pi = 0; pi < 2; ++pi) {
                    int mf = 2 * mg + pi;
                    long aoffP = (((long)ks * 16 + mf) * 64 + lane) * 8;
                    short8 ahP = *(const short8*)(AhB + aoffP);
                    short8 alP = *(const short8*)(AlB + aoffP);
#pragma unroll
                    for (int c = 0; c < 3; ++c) {
                        accP[pi][c] = __builtin_amdgcn_mfma_f32_16x16x32_bf16(ahP, bh[c], accP[pi][c], 0, 0, 0);
                        accP[pi][c] = __builtin_amdgcn_mfma_f32_16x16x32_bf16(ahP, bl[c], accP[pi][c], 0, 0, 0);
                        accP[pi][c] = __builtin_amdgcn_mfma_f32_16x16x32_bf16(alP, bh[c], accP[pi][c], 0, 0, 0);
                    }
                    long aoffD = (((long)ks * 16 + (8 + mf)) * 64 + lane) * 8;
                    short8 ahD = *(const short8*)(AhB + aoffD);
                    short8 alD = *(const short8*)(AlB + aoffD);
#pragma unroll
                    for (int c = 0; c < 3; ++c) {
                        accD[pi][c] = __builtin_amdgcn_mfma_f32_16x16x32_bf16(ahD, bh[c], accD[pi][c], 0, 0, 0);
                        accD[pi][c] = __builtin_amdgcn_mfma_f32_16x16x32_bf16(ahD, bl[c], accD[pi][c], 0, 0, 0);
                        accD[pi][c] = __builtin_amdgcn_mfma_f32_16x16x32_bf16(alD, bh[c], accD[pi][c], 0, 0, 0);
                    }
                }
            }
#pragma unroll
            for (int pi = 0; pi < 2; ++pi) {
                int obase = 32 * mg + 16 * pi + ((lane >> 4) << 2);
                float Pv[3][4];
#pragma unroll
                for (int r = 0; r < 4; ++r) {
                    int o = obase + r;
                    float P[3], D[3];
#pragma unroll
                    for (int c = 0; c < 3; ++c) {
                        P[c] = accP[pi][c][r] + biasPs[o][c];
                        D[c] = accD[pi][c][r] + biasDs[o][c];
                    }
                    float dot = P[0] * D[0] + P[1] * D[1] + P[2] * D[2];
                    float dsq = D[0] * D[0] + D[1] * D[1] + D[2] * D[2];
                    if (dot < 0.0f) {
                        float s = dot / (dsq + 1e-6f);
                        P[0] -= s * D[0]; P[1] -= s * D[1]; P[2] -= s * D[2];
                    }
                    Pv[0][r] = P[0]; Pv[1][r] = P[1]; Pv[2][r] = P[2];
                }
#pragma unroll
                for (int c = 0; c < 3; ++c) {
                    unsigned short hs[4], ls[4];
#pragma unroll
                    for (int r = 0; r < 4; ++r) {
                        hs[r] = f2bf(Pv[c][r]);
                        ls[r] = f2bf(Pv[c][r] - bf2f(hs[r]));
                    }
                    long ooff = ((long)(b * 3 + c) * N + ncol) * 128 + obase;
                    *(ushort4*)(f0h + ooff) = make_ushort4(hs[0], hs[1], hs[2], hs[3]);
                    *(ushort4*)(f0l + ooff) = make_ushort4(ls[0], ls[1], ls[2], ls[3]);
                    int li = ((obase >> 3) << 7) + ((lane & 15) << 3) + (obase & 7);
                    *(ushort4*)&ylds[ng][c][0][li] = make_ushort4(hs[0], hs[1], hs[2], hs[3]);
                    *(ushort4*)&ylds[ng][c][1][li] = make_ushort4(ls[0], ls[1], ls[2], ls[3]);
                }
            }
            __syncthreads();
            // fused Wout partial: out1 (+)= Wout_l @ y2
            f32x4 accO[2][3] = {};
            const unsigned short* AoH = Aph + 262144 + (long)l * 16384;
            const unsigned short* AoL = Apl + 262144 + (long)l * 16384;
#pragma unroll
            for (int ks = 0; ks < 4; ++ks) {
                short8 yh[3], yl[3];
                int li = (((ks << 2) + (lane >> 4)) << 7) + ((lane & 15) << 3);
#pragma unroll
                for (int c = 0; c < 3; ++c) {
                    yh[c] = *(const short8*)&ylds[ng][c][0][li];
                    yl[c] = *(const short8*)&ylds[ng][c][1][li];
                }
#pragma unroll
                for (int pi = 0; pi < 2; ++pi) {
                    int mf = 2 * mg + pi;
                    long aoff = (((long)ks * 8 + mf) * 64 + lane) * 8;
                    short8 ah = *(const short8*)(AoH + aoff);
                    short8 al = *(const short8*)(AoL + aoff);
#pragma unroll
                    for (int c = 0; c < 3; ++c) {
                        accO[pi][c] = __builtin_amdgcn_mfma_f32_16x16x32_bf16(ah, yh[c], accO[pi][c], 0, 0, 0);
                        accO[pi][c] = __builtin_amdgcn_mfma_f32_16x16x32_bf16(ah, yl[c], accO[pi][c], 0, 0, 0);
                        accO[pi][c] = __builtin_amdgcn_mfma_f32_16x16x32_bf16(al, yh[c], accO[pi][c], 0, 0, 0);
                    }
                }
            }
#pragma unroll
            for (int pi = 0; pi < 2; ++pi) {
                int obase = 32 * mg + 16 * pi + ((lane >> 4) << 2);
#pragma unroll
                for (int r = 0; r < 4; ++r) {
                    int o = obase + r;
#pragma unroll
                    for (int c = 0; c < 3; ++c) {
                        long off = ((long)(b * 128 + o) * 3 + c) * N + ncol;
                        float v = accO[pi][c][r];
                        if (l > 0) v += out1[off];
                        out1[off] = v;
                    }
                }
            }
            __syncthreads();     // protect ylds before next layer reuses it
        }
        grid_bar(bar, 256 * (++nbar));
    }

    // ================= final: out0 = mean_N(out1), 3 rows per block =================
#pragma unroll
    for (int j = 0; j < 3; ++j) {
        int row = blockIdx.x * 3 + j;          // (b*128+o)*3+c, 0..767
        const float* p = out1 + (long)row * N;
        float s = 0.f;
        for (int i = t; i < N; i += 512) s += p[i];
#pragma unroll
        for (int d = 1; d < 64; d <<= 1) s += __shfl_xor(s, d);
        if (lane == 0) red[0][w] = s;
        __syncthreads();
        if (t == 0) {
            float r = 0.f;
#pragma unroll
            for (int kk = 0; kk < 8; ++kk) r += red[0][kk];
            out0[row] = r * (1.0f / 4096.0f);
        }
        __syncthreads();
    }
}

extern "C" void kernel_launch(void* const* d_in, const int* in_sizes, int n_in,
                              void* d_out, int out_size, void* d_ws, size_t ws_size,
                              hipStream_t stream) {
    const float* x    = (const float*)d_in[0];
    const float* Win  = (const float*)d_in[1];
    const float* Uin  = (const float*)d_in[2];
    const float* Wl   = (const float*)d_in[3];
    const float* Ul   = (const float*)d_in[4];
    const float* Wg   = (const float*)d_in[5];
    const float* Ug   = (const float*)d_in[6];
    const float* Wout = (const float*)d_in[7];

    const int B = 2, N = 4096, H = 128;
    float* out0 = (float*)d_out;                 // (B,128,3) mean
    float* out1 = out0 + (long)B * H * 3;        // (B,128,3,N) fp32

    float* ws = (float*)d_ws;
    long off = 0;
    float4* pts4 = (float4*)ws;                  off += (long)B * N * 4;
    int* idx = (int*)(ws + off);                 off += (long)B * N * 16;
    const long ACT = (long)B * 3 * N * H;        // ushort count
    unsigned short* f0h = (unsigned short*)(ws + off);  off += ACT / 2;
    unsigned short* f0l = (unsigned short*)(ws + off);  off += ACT / 2;
    unsigned short* y1h = (unsigned short*)(ws + off);  off += ACT / 2;
    unsigned short* y1l = (unsigned short*)(ws + off);  off += ACT / 2;
    unsigned short* Aph = (unsigned short*)(ws + off);  off += 327680 / 2;
    unsigned short* Apl = (unsigned short*)(ws + off);  off += 327680 / 2;
    float* part  = ws + off;                     off += 6L * 256 * 128;
    float* yg    = ws + off;                     off += B * H * 3;
    int* bar     = (int*)(ws + off);             off += 16;
    // ~27.6 MB of workspace

    setup_kernel<<<1280, 256, 0, stream>>>(x, pts4, Wl, Ul, Wg, Ug, Wout,
                                           Aph, Apl, bar, N, B);
    knn_kernel<<<B * (N / 16), 1024, 0, stream>>>(pts4, idx, N);
    edge_kernel<<<B * (N / 8), 256, 0, stream>>>(pts4, idx, Win, Uin, f0h, f0l, N);
    mega_kernel<<<256, 512, 0, stream>>>(Aph, Apl, f0h, f0l, y1h, y1l,
                                         Wg, Ug, part, yg, out1, out0, bar);
}

// Round 9
// 321.041 us; speedup vs baseline: 3.7152x; 3.7152x over previous
//
#include <hip/hip_runtime.h>
#include <hip/hip_bf16.h>
#include <cfloat>

// VecPointNet on MI355X, round 9:
//  - mega-kernel (r8) abandoned: atomic grid barrier ~70us each on MI355X.
//  - Restored r7 pipeline structure with r6-quality knn.
//  - kNN: stale-threshold batched inserts (T refreshed once per 64-chunk, not
//    per insert) + u32-orderable key with idx shadow. Removes 1 of 3 dependent
//    cross-lane hops per insert; inserts of non-qualifying candidates are
//    provable no-ops, so correctness and jax.lax.top_k tie semantics hold.
//  - ygred + bias fused into one 6-block kernel (block bc owns yg[b,:,c]).
//  Dispatches: setup, knn, edge, 4x[gemm0, ygredbias, gemm1], reduce_mean = 16.

typedef __attribute__((ext_vector_type(8))) short short8;
typedef __attribute__((ext_vector_type(4))) float f32x4;

__device__ __forceinline__ unsigned short f2bf(float f) {
    union { float f; unsigned u; } v; v.f = f;
    unsigned r = v.u + 0x7fffu + ((v.u >> 16) & 1u);
    return (unsigned short)(r >> 16);
}
__device__ __forceinline__ float bf2f(unsigned short h) {
    union { unsigned u; float f; } v; v.u = ((unsigned)h) << 16;
    return v.f;
}

// ---------------- setup: prep (pts4) + weight pack ----------------
__global__ __launch_bounds__(256) void setup_kernel(const float* __restrict__ x,
                                                    float4* __restrict__ pts4,
                                                    const float* __restrict__ Wl,
                                                    const float* __restrict__ Ul,
                                                    const float* __restrict__ Wg,
                                                    const float* __restrict__ Ug,
                                                    const float* __restrict__ Wout,
                                                    unsigned short* __restrict__ Ah,
                                                    unsigned short* __restrict__ Al,
                                                    int N, int B) {
    int t = blockIdx.x * 256 + threadIdx.x;     // 0..327679
    if (t < B * N) {
        int b = t / N, n = t - b * N;
        const float* xb = x + (long)b * 3 * N;
        float px = xb[n], py = xb[N + n], pz = xb[2 * N + n];
        pts4[t] = make_float4(px, py, pz, px * px + py * py + pz * pz);
    }
    int g, r, M; long base;
    if (t < 262144) { g = t >> 15; r = t & 32767; M = 256; base = (long)g << 15; }
    else { int t2 = t - 262144; g = 8 + (t2 >> 14); r = t2 & 16383; M = 128;
           base = 262144 + (long)(g - 8) * 16384; }
    int MF = M >> 4;
    int ks = r / (MF * 512);
    int mf = (r >> 9) % MF;
    int lane = (r >> 3) & 63;
    int j = r & 7;
    int m = mf * 16 + (lane & 15);
    int k = ks * 32 + ((lane >> 4) << 3) + j;
    const float* src; int ldw; int row;
    if (g < 4) {
        ldw = 128; row = m & 127;
        src = (m < 128) ? (Wl + (long)g * 128 * 128) : (Ul + (long)g * 128 * 128);
    } else if (g < 8) {
        ldw = 256; row = m & 127;
        int l = g - 4;
        src = (m < 128) ? (Wg + (long)l * 128 * 256) : (Ug + (long)l * 128 * 256);
    } else {
        ldw = 512; row = m;
        src = Wout + (g - 8) * 128;
    }
    float v = src[(long)row * ldw + k];
    unsigned short h = f2bf(v);
    Ah[base + r] = h;
    Al[base + r] = f2bf(v - bf2f(h));
}

// ---------------- knn: wave/query, stale-T batched inserts, u32 key + idx ----------------
// Sorted (u,idx) lex-ascending list in lanes 0..15. T = lane15's pair, refreshed
// once per chunk. Inserting a candidate >= k[15] is a no-op, so stale T only
// over-admits harmlessly. Distinct candidates have distinct idx -> total order.
__global__ __launch_bounds__(1024) void knn_kernel(const float4* __restrict__ pts4,
                                                   int* __restrict__ idxOut, int N) {
    __shared__ float4 cbuf[4096];   // 64 KB
    int t = threadIdx.x;
    int tilesPerB = N / 16;
    int b = blockIdx.x / tilesPerB;
    int q = (blockIdx.x % tilesPerB) * 16 + (t >> 6);
    int lane = t & 63;

    for (int i = t; i < N; i += 1024) cbuf[i] = pts4[b * N + i];
    __syncthreads();

    float4 Q = cbuf[q];
    unsigned ku = 0xFFFFFFFFu; int ki = 0x7fffffff;   // lanes 0..15: sorted list
    unsigned Tu = 0xFFFFFFFFu; int Ti = 0x7fffffff;   // stale 16th-best

    for (int c0 = 0; c0 < N; c0 += 64) {
        float4 C = cbuf[c0 + lane];
        float dot = Q.x * C.x + Q.y * C.y + Q.z * C.z;
        float d2 = Q.w + C.w - 2.0f * dot;            // same formula as reference
        unsigned u = __float_as_uint(d2);
        u ^= (unsigned)((int)u >> 31) | 0x80000000u;  // orderable uint
        int ci = c0 + lane;
        bool qual = (u < Tu) || (u == Tu && ci < Ti);
        unsigned long long mask = __ballot(qual);
        while (mask) {
            int src = __ffsll(mask) - 1;
            mask &= mask - 1;
            unsigned vu = (unsigned)__shfl((int)u, src);
            int      vi = __shfl(ci, src);
            unsigned kum1 = (unsigned)__shfl_up((int)ku, 1);
            int      kim1 = __shfl_up(ki, 1);
            if (lane == 0) { kum1 = 0u; kim1 = (-2147483647 - 1); }
            bool lem1 = (vu < kum1) || (vu == kum1 && vi < kim1);  // v < k[j-1]
            bool ltj  = (vu < ku)   || (vu == ku   && vi < ki);    // v < k[j]
            unsigned knu = lem1 ? kum1 : (ltj ? vu : ku);
            int      kni = lem1 ? kim1 : (ltj ? vi : ki);
            if (lane < 16) { ku = knu; ki = kni; }
        }
        Tu = (unsigned)__shfl((int)ku, 15);
        Ti = __shfl(ki, 15);
    }
    if (lane < 16) idxOut[(b * N + q) * 16 + lane] = ki;
}

// ---------------- edge features + input LNA + mean over K -> f0 bf16 hi/lo ----------------
__global__ __launch_bounds__(256) void edge_kernel(const float4* __restrict__ pts4,
                                                   const int* __restrict__ idx,
                                                   const float* __restrict__ Win,
                                                   const float* __restrict__ Uin,
                                                   unsigned short* __restrict__ Yh,
                                                   unsigned short* __restrict__ Yl,
                                                   int N) {
    __shared__ float4 nbuf[8][16];
    __shared__ float4 cpt[8];
    int nTiles = N / 8;
    int b = blockIdx.x / nTiles;
    int n0 = (blockIdx.x % nTiles) * 8;
    int t = threadIdx.x;
    if (t < 128) {
        int pl = t >> 4, k = t & 15;
        int nb = idx[(b * N + n0 + pl) * 16 + k];
        nbuf[pl][k] = pts4[b * N + nb];
    } else if (t < 136) {
        cpt[t - 128] = pts4[b * N + n0 + (t - 128)];
    }
    __syncthreads();
    int o = t & 127, h = t >> 7;
    float w0 = Win[o * 3], w1 = Win[o * 3 + 1], w2 = Win[o * 3 + 2];
    float u0 = Uin[o * 3], u1 = Uin[o * 3 + 1], u2 = Uin[o * 3 + 2];
    for (int pl = h * 4; pl < h * 4 + 4; ++pl) {
        float4 c4 = cpt[pl];
        float inv = 1.0f / fmaxf(sqrtf(c4.w), 1e-12f);
        float ax = c4.x * inv, ay = c4.y * inv, az = c4.z * inv;
        float a0 = 0.f, a1 = 0.f, a2 = 0.f;
        for (int k = 0; k < 16; ++k) {
            float4 nb = nbuf[pl][k];
            float cr0 = ay * nb.z - az * nb.y;
            float cr1 = az * nb.x - ax * nb.z;
            float cr2 = ax * nb.y - ay * nb.x;
            float df0 = nb.x - c4.x, df1 = nb.y - c4.y, df2 = nb.z - c4.z;
            float P0 = w0 * cr0 + w1 * df0 + w2 * c4.x;
            float P1 = w0 * cr1 + w1 * df1 + w2 * c4.y;
            float P2 = w0 * cr2 + w1 * df2 + w2 * c4.z;
            float D0 = u0 * cr0 + u1 * df0 + u2 * c4.x;
            float D1 = u0 * cr1 + u1 * df1 + u2 * c4.y;
            float D2 = u0 * cr2 + u1 * df2 + u2 * c4.z;
            float dot = P0 * D0 + P1 * D1 + P2 * D2;
            float dsq = D0 * D0 + D1 * D1 + D2 * D2;
            if (dot < 0.0f) {
                float s = dot / (dsq + 1e-6f);
                P0 -= s * D0; P1 -= s * D1; P2 -= s * D2;
            }
            a0 += P0; a1 += P1; a2 += P2;
        }
        float vals[3] = { a0 * (1.0f / 16.0f), a1 * (1.0f / 16.0f), a2 * (1.0f / 16.0f) };
        long n = n0 + pl;
#pragma unroll
        for (int c = 0; c < 3; ++c) {
            long off = ((long)(b * 3 + c) * 4096 + n) * 128 + o;
            unsigned short hh = f2bf(vals[c]);
            Yh[off] = hh;
            Yl[off] = f2bf(vals[c] - bf2f(hh));
        }
    }
}

// ---------------- MFMA GEMM, bf16x3 (r7 structure, measured-good) ----------------
// MODE 0: LNA; emits per-16col yg partials. MODE 1: LNA + bias + fused Wout.
template<int MODE>
__global__ __launch_bounds__(512, 1) void gemm_kernel(
    const unsigned short* __restrict__ Aph, const unsigned short* __restrict__ Apl,
    long aOff, long aOffOut,
    const unsigned short* __restrict__ Bh, const unsigned short* __restrict__ Bl,
    const float* __restrict__ biasP, const float* __restrict__ biasD,
    unsigned short* __restrict__ Oh, unsigned short* __restrict__ Ol,
    float* __restrict__ Ofp, float* __restrict__ part, int accum)
{
    const int N = 4096;
    __shared__ unsigned short ylds[MODE == 1 ? 2 : 1][3][2][2048];
    int t = threadIdx.x;
    int lane = t & 63, w = t >> 6;
    int mg = w >> 1, ng = w & 1;
    int b = blockIdx.x >> 7;
    int tile = blockIdx.x & 127;
    int ncol = tile * 32 + ng * 16 + (lane & 15);
    int kq = (lane >> 4) << 3;

    f32x4 accP[2][3] = {};
    f32x4 accD[2][3] = {};

    const unsigned short* AhB = Aph + aOff;
    const unsigned short* AlB = Apl + aOff;

#pragma unroll
    for (int ks = 0; ks < 4; ++ks) {
        short8 bh[3], bl[3];
#pragma unroll
        for (int c = 0; c < 3; ++c) {
            long boff = ((long)(b * 3 + c) * N + ncol) * 128 + ks * 32 + kq;
            bh[c] = *(const short8*)(Bh + boff);
            bl[c] = *(const short8*)(Bl + boff);
        }
#pragma unroll
        for (int pi = 0; pi < 2; ++pi) {
            int mf = 2 * mg + pi;
            long aoffP = (((long)ks * 16 + mf) * 64 + lane) * 8;
            short8 ahP = *(const short8*)(AhB + aoffP);
            short8 alP = *(const short8*)(AlB + aoffP);
#pragma unroll
            for (int c = 0; c < 3; ++c) {
                accP[pi][c] = __builtin_amdgcn_mfma_f32_16x16x32_bf16(ahP, bh[c], accP[pi][c], 0, 0, 0);
                accP[pi][c] = __builtin_amdgcn_mfma_f32_16x16x32_bf16(ahP, bl[c], accP[pi][c], 0, 0, 0);
                accP[pi][c] = __builtin_amdgcn_mfma_f32_16x16x32_bf16(alP, bh[c], accP[pi][c], 0, 0, 0);
            }
            long aoffD = (((long)ks * 16 + (8 + mf)) * 64 + lane) * 8;
            short8 ahD = *(const short8*)(AhB + aoffD);
            short8 alD = *(const short8*)(AlB + aoffD);
#pragma unroll
            for (int c = 0; c < 3; ++c) {
                accD[pi][c] = __builtin_amdgcn_mfma_f32_16x16x32_bf16(ahD, bh[c], accD[pi][c], 0, 0, 0);
                accD[pi][c] = __builtin_amdgcn_mfma_f32_16x16x32_bf16(ahD, bl[c], accD[pi][c], 0, 0, 0);
                accD[pi][c] = __builtin_amdgcn_mfma_f32_16x16x32_bf16(alD, bh[c], accD[pi][c], 0, 0, 0);
            }
        }
    }

#pragma unroll
    for (int pi = 0; pi < 2; ++pi) {
        int obase = 32 * mg + 16 * pi + ((lane >> 4) << 2);
        float Pv[3][4];
#pragma unroll
        for (int r = 0; r < 4; ++r) {
            int o = obase + r;
            float P[3], D[3];
#pragma unroll
            for (int c = 0; c < 3; ++c) {
                P[c] = accP[pi][c][r];
                D[c] = accD[pi][c][r];
                if (MODE == 1) {
                    long bb = ((long)(b * 128 + o)) * 3 + c;
                    P[c] += biasP[bb];
                    D[c] += biasD[bb];
                }
            }
            float dot = P[0] * D[0] + P[1] * D[1] + P[2] * D[2];
            float dsq = D[0] * D[0] + D[1] * D[1] + D[2] * D[2];
            if (dot < 0.0f) {
                float s = dot / (dsq + 1e-6f);
                P[0] -= s * D[0]; P[1] -= s * D[1]; P[2] -= s * D[2];
            }
            Pv[0][r] = P[0]; Pv[1][r] = P[1]; Pv[2][r] = P[2];
        }
#pragma unroll
        for (int c = 0; c < 3; ++c) {
            unsigned short hs[4], ls[4];
#pragma unroll
            for (int r = 0; r < 4; ++r) {
                hs[r] = f2bf(Pv[c][r]);
                ls[r] = f2bf(Pv[c][r] - bf2f(hs[r]));
            }
            long ooff = ((long)(b * 3 + c) * N + ncol) * 128 + obase;
            *(ushort4*)(Oh + ooff) = make_ushort4(hs[0], hs[1], hs[2], hs[3]);
            *(ushort4*)(Ol + ooff) = make_ushort4(ls[0], ls[1], ls[2], ls[3]);
            if (MODE == 1) {
                int li = ((obase >> 3) << 7) + ((lane & 15) << 3) + (obase & 7);
                *(ushort4*)&ylds[ng][c][0][li] = make_ushort4(hs[0], hs[1], hs[2], hs[3]);
                *(ushort4*)&ylds[ng][c][1][li] = make_ushort4(ls[0], ls[1], ls[2], ls[3]);
            }
        }
        if (MODE == 0) {
#pragma unroll
            for (int c = 0; c < 3; ++c) {
#pragma unroll
                for (int r = 0; r < 4; ++r) {
                    float v = Pv[c][r];
                    v += __shfl_xor(v, 1);
                    v += __shfl_xor(v, 2);
                    v += __shfl_xor(v, 4);
                    v += __shfl_xor(v, 8);
                    if ((lane & 15) == 0)
                        part[((long)(b * 3 + c) * 256 + tile * 2 + ng) * 128 + (obase + r)] = v;
                }
            }
        }
    }

    if (MODE == 1) {
        __syncthreads();
        f32x4 accO[2][3] = {};
        const unsigned short* AoH = Aph + aOffOut;
        const unsigned short* AoL = Apl + aOffOut;
#pragma unroll
        for (int ks = 0; ks < 4; ++ks) {
            short8 yh[3], yl[3];
            int li = (((ks << 2) + (lane >> 4)) << 7) + ((lane & 15) << 3);
#pragma unroll
            for (int c = 0; c < 3; ++c) {
                yh[c] = *(const short8*)&ylds[ng][c][0][li];
                yl[c] = *(const short8*)&ylds[ng][c][1][li];
            }
#pragma unroll
            for (int pi = 0; pi < 2; ++pi) {
                int mf = 2 * mg + pi;
                long aoff = (((long)ks * 8 + mf) * 64 + lane) * 8;
                short8 ah = *(const short8*)(AoH + aoff);
                short8 al = *(const short8*)(AoL + aoff);
#pragma unroll
                for (int c = 0; c < 3; ++c) {
                    accO[pi][c] = __builtin_amdgcn_mfma_f32_16x16x32_bf16(ah, yh[c], accO[pi][c], 0, 0, 0);
                    accO[pi][c] = __builtin_amdgcn_mfma_f32_16x16x32_bf16(ah, yl[c], accO[pi][c], 0, 0, 0);
                    accO[pi][c] = __builtin_amdgcn_mfma_f32_16x16x32_bf16(al, yh[c], accO[pi][c], 0, 0, 0);
                }
            }
        }
#pragma unroll
        for (int pi = 0; pi < 2; ++pi) {
            int obase = 32 * mg + 16 * pi + ((lane >> 4) << 2);
#pragma unroll
            for (int r = 0; r < 4; ++r) {
                int o = obase + r;
#pragma unroll
                for (int c = 0; c < 3; ++c) {
                    long off = ((long)(b * 128 + o) * 3 + c) * N + ncol;
                    float v = accO[pi][c][r];
                    if (accum) v += Ofp[off];
                    Ofp[off] = v;
                }
            }
        }
    }
}

// ---------------- fused yg reduce + bias: 6 blocks (b*3+c), 1024 threads ----------------
// part: [bc][seg 0..255][o]; yg slice lives in LDS; bias dot done in-block.
__global__ __launch_bounds__(1024) void ygredbias_kernel(const float* __restrict__ part,
                                                         const float* __restrict__ Wg,
                                                         const float* __restrict__ Ug,
                                                         float* __restrict__ biasP,
                                                         float* __restrict__ biasD) {
    __shared__ float red[8][128];
    __shared__ float ygs[128];
    int bc = blockIdx.x;
    int t = threadIdx.x;
    int o = t & 127, g = t >> 7;
    float s = 0.f;
    for (int seg = g * 32; seg < g * 32 + 32; ++seg)
        s += part[((long)bc * 256 + seg) * 128 + o];
    red[g][o] = s;
    __syncthreads();
    if (t < 128) {
        float r = 0.f;
#pragma unroll
        for (int k = 0; k < 8; ++k) r += red[k][t];
        ygs[t] = r * (1.0f / 4096.0f);
    }
    __syncthreads();
    if (t < 256) {
        int oo = t & 127; bool isD = t >= 128;
        const float* row = (isD ? Ug : Wg) + oo * 256 + 128;
        float s2 = 0.f;
        for (int i = 0; i < 128; ++i) s2 = fmaf(row[i], ygs[i], s2);
        int b = bc / 3, c = bc % 3;
        (isD ? biasD : biasP)[((long)(b * 128 + oo)) * 3 + c] = s2;
    }
}

// ---------------- mean over N per (b, o, c) row of fp32 out1 ----------------
__global__ __launch_bounds__(256) void reduce_mean_kernel(const float* __restrict__ src, long bs,
                                                          float* __restrict__ dst, int N) {
    __shared__ float red[256];
    int row = blockIdx.x;
    int b = row / 384; int rr = row % 384;
    const float* p = src + (long)b * bs + (long)rr * N;
    float s = 0.f;
    for (int i = threadIdx.x; i < N; i += 256) s += p[i];
    red[threadIdx.x] = s;
    __syncthreads();
    for (int st = 128; st > 0; st >>= 1) {
        if (threadIdx.x < st) red[threadIdx.x] += red[threadIdx.x + st];
        __syncthreads();
    }
    if (threadIdx.x == 0) dst[row] = red[0] / (float)N;
}

extern "C" void kernel_launch(void* const* d_in, const int* in_sizes, int n_in,
                              void* d_out, int out_size, void* d_ws, size_t ws_size,
                              hipStream_t stream) {
    const float* x    = (const float*)d_in[0];
    const float* Win  = (const float*)d_in[1];
    const float* Uin  = (const float*)d_in[2];
    const float* Wl   = (const float*)d_in[3];
    const float* Ul   = (const float*)d_in[4];
    const float* Wg   = (const float*)d_in[5];
    const float* Ug   = (const float*)d_in[6];
    const float* Wout = (const float*)d_in[7];

    const int B = 2, N = 4096, H = 128;
    float* out0 = (float*)d_out;                 // (B,128,3) mean
    float* out1 = out0 + (long)B * H * 3;        // (B,128,3,N) fp32

    float* ws = (float*)d_ws;
    long off = 0;
    float4* pts4 = (float4*)ws;                  off += (long)B * N * 4;
    int* idx = (int*)(ws + off);                 off += (long)B * N * 16;
    const long ACT = (long)B * 3 * N * H;        // ushort count
    unsigned short* f0h = (unsigned short*)(ws + off);  off += ACT / 2;
    unsigned short* f0l = (unsigned short*)(ws + off);  off += ACT / 2;
    unsigned short* y1h = (unsigned short*)(ws + off);  off += ACT / 2;
    unsigned short* y1l = (unsigned short*)(ws + off);  off += ACT / 2;
    unsigned short* Aph = (unsigned short*)(ws + off);  off += 327680 / 2;
    unsigned short* Apl = (unsigned short*)(ws + off);  off += 327680 / 2;
    float* part  = ws + off;                     off += 6L * 256 * 128;
    float* biasP = ws + off;                     off += B * H * 3;
    float* biasD = ws + off;                     off += B * H * 3;
    // ~27.6 MB of workspace

    long bs128 = (long)H * 3 * N;

    setup_kernel<<<1280, 256, 0, stream>>>(x, pts4, Wl, Ul, Wg, Ug, Wout, Aph, Apl, N, B);
    knn_kernel<<<B * (N / 16), 1024, 0, stream>>>(pts4, idx, N);
    edge_kernel<<<B * (N / 8), 256, 0, stream>>>(pts4, idx, Win, Uin, f0h, f0l, N);

    for (int l = 0; l < 4; ++l) {
        gemm_kernel<0><<<256, 512, 0, stream>>>(
            Aph, Apl, (long)l * 32768, 0, f0h, f0l, nullptr, nullptr,
            y1h, y1l, nullptr, part, 0);
        ygredbias_kernel<<<6, 1024, 0, stream>>>(part,
            Wg + (long)l * H * 256, Ug + (long)l * H * 256, biasP, biasD);
        gemm_kernel<1><<<256, 512, 0, stream>>>(
            Aph, Apl, (long)(4 + l) * 32768, 262144 + (long)l * 16384,
            y1h, y1l, biasP, biasD, f0h, f0l, out1, nullptr, l > 0 ? 1 : 0);
    }
    reduce_mean_kernel<<<B * H * 3, 256, 0, stream>>>(out1, bs128, out0, N);
}